// Round 1
// baseline (223.007 us; speedup 1.0000x reference)
//
#include <hip/hip_runtime.h>

// y[..., 2k]   = T[k][0][0]*x[2k] + T[k][0][1]*x[2k+1]
// y[..., 2k+1] = T[k][1][0]*x[2k] + T[k][1][1]*x[2k+1]
// twiddle flat layout: tw[k*4 + a*2 + b] -> one float4 per pair k.

__global__ __launch_bounds__(256) void butterfly_kernel(
    const float4* __restrict__ x,
    const float4* __restrict__ tw,   // tw[k] = {t00, t01, t10, t11} for pair k
    float4* __restrict__ y,
    int n4,        // total float4 count = total_floats / 4
    int row4_mask) // (4096/4) - 1, power-of-2 mask for within-row position
{
    int i = blockIdx.x * blockDim.x + threadIdx.x;
    if (i >= n4) return;

    int p = i & row4_mask;        // float4 index within the 4096-wide row
    // this float4 covers floats [4p, 4p+3] -> pairs k0 = 2p, k1 = 2p+1
    float4 xv = x[i];
    float4 t0 = tw[2 * p];
    float4 t1 = tw[2 * p + 1];

    float4 yv;
    yv.x = t0.x * xv.x + t0.y * xv.y;
    yv.y = t0.z * xv.x + t0.w * xv.y;
    yv.z = t1.x * xv.z + t1.y * xv.w;
    yv.w = t1.z * xv.z + t1.w * xv.w;

    y[i] = yv;
}

extern "C" void kernel_launch(void* const* d_in, const int* in_sizes, int n_in,
                              void* d_out, int out_size, void* d_ws, size_t ws_size,
                              hipStream_t stream) {
    const float4* x  = (const float4*)d_in[0];   // (4, 2048, 4096) fp32
    const float4* tw = (const float4*)d_in[1];   // (2048, 2, 2) fp32
    float4* y = (float4*)d_out;

    int n4 = out_size / 4;            // 8388608 float4s
    int row4_mask = (4096 / 4) - 1;   // 1023

    dim3 block(256);
    dim3 grid((n4 + 255) / 256);
    butterfly_kernel<<<grid, block, 0, stream>>>(x, tw, y, n4, row4_mask);
}